// Round 16
// baseline (250.795 us; speedup 1.0000x reference)
//
#include <hip/hip_runtime.h>

// LCT FK-migration: 3D FFT(512,256,256) -> Stolt trilinear resample -> 3D IFFT -> |.|^2
// Single 256 MiB workspace buffer V = [512][256][256] cpx, flat (z<<16)+(y<<8)+x.
// x/y spectra stored FFTSHIFTED with the half-pixel Stolt x/y blurs folded into the
// forward x/y FFT stores (ix = xs-0.5, iy = ys-0.5 exactly => fx=fy=0.5 fixed blur).
// Z-stage FUSED (k_fftz_fused): block for dest column (y,x-tile) fwd-FFTs its partner
// source column ((y+128)&255,(x+128)&255) — stage 0 straight from global, h4/lo4
// half-butterflies, fwd bins at NATURAL LDS rows — then z-only Stolt gather from LDS
// into inverse-stage-0 registers, inverse FFT, direct store to planes 256..511.
// Round-16: k_fft_y is RADIX-16 (2 stages): stage 0 from global into 16 registers
// (dft16 = two in-register radix-4 levels; dft16_h8 half-input fwd), outer twiddle,
// one LDS round; stage 1 on thread-owned consecutive rows (no cross-thread hazard);
// inverse crops via dft16_lo8 + direct reg->global store (1 barrier total).
// Complex algebra as ext_vector floats for packed v_pk_*_f32 (VOP3P).
// Twiddles stored as float4 (c, c, -s, s): cmul(a,w) = a*wl + swap(a)*wh.

typedef float __attribute__((ext_vector_type(2))) cpx;
typedef float __attribute__((ext_vector_type(4))) cpx2;   // two cpx (adjacent x columns)

__device__ float4 g_tw4[512];   // (c, c, -s, s), (c,s) = exp(-2*pi*i*k/512)

__device__ __forceinline__ cpx cswap(cpx a){ return __builtin_shufflevector(a, a, 1, 0); }
__device__ __forceinline__ cpx cmji(cpx a){ return cswap(a)*(cpx){1.0f, -1.0f}; }   // -i*a
__device__ __forceinline__ cpx cmpi(cpx a){ return cswap(a)*(cpx){-1.0f, 1.0f}; }   // +i*a

// base-4 digit reversal of an 8-bit index
__device__ __forceinline__ int rev4_8(int k){
    return ((k & 3) << 6) | ((k & 12) << 2) | ((k >> 2) & 12) | (k >> 6);
}
// swap the two base-4 digits of a 4-bit index (position<->bin map inside dft16)
__device__ __forceinline__ int prm(int q){ return ((q & 3) << 2) | (q >> 2); }

// ---------------- twiddle table (double-computed for accuracy) ----------------
__global__ void k_tw(){
    int j = threadIdx.x;                        // 512 threads
    double a = -2.0*3.14159265358979323846*(double)j/512.0;
    float c = (float)cos(a), s = (float)sin(a);
    g_tw4[j] = make_float4(c, c, -s, s);
}

template<bool INV>
__device__ __forceinline__ cpx twmul(cpx a, int k){
    float4 t = g_tw4[k & 511];
    cpx wl = {t.x, t.y};
    cpx wh = {t.z, t.w};
    cpx r = a*wl;
    return INV ? (r - cswap(a)*wh) : (r + cswap(a)*wh);
}

// ---------------- radix-4 butterflies ----------------
template<bool INV>
__device__ __forceinline__ void dft4(cpx* x){
    cpx e0 = x[0] + x[2], e1 = x[0] - x[2];
    cpx o0 = x[1] + x[3], o1 = x[1] - x[3];
    x[0] = e0 + o0;
    x[2] = e0 - o0;
    cpx j1 = INV ? cmpi(o1) : cmji(o1);
    x[1] = e1 + j1;
    x[3] = e1 - j1;
}
template<bool INV>
__device__ __forceinline__ void dft4_h2(cpx* x){
    cpx a0 = x[0], a1 = x[1];
    x[0] = a0 + a1;
    x[2] = a0 - a1;
    cpx j1 = INV ? cmpi(a1) : cmji(a1);
    x[1] = a0 + j1;
    x[3] = a0 - j1;
}
template<bool INV>
__device__ __forceinline__ void dft4_lo2(cpx* x){
    cpx e0 = x[0] + x[2], e1 = x[0] - x[2];
    cpx o0 = x[1] + x[3], o1 = x[1] - x[3];
    x[0] = e0 + o0;
    x[1] = e1 + (INV ? cmpi(o1) : cmji(o1));
}

// ---------------- radix-16 butterflies (two radix-4 DIF levels in registers) ----------------
// x[] indexed by POSITION; natural bin k ends at register prm(k).
template<bool INV>
__device__ __forceinline__ void dft16(cpx* x){
    #pragma unroll
    for (int j2 = 0; j2 < 4; ++j2){
        cpx y[4] = {x[j2], x[j2+4], x[j2+8], x[j2+12]};
        dft4<INV>(y);
        if (j2){
            #pragma unroll
            for (int r = 1; r < 4; ++r) y[r] = twmul<INV>(y[r], 32*j2*r);
        }
        x[j2] = y[0]; x[j2+4] = y[1]; x[j2+8] = y[2]; x[j2+12] = y[3];
    }
    #pragma unroll
    for (int g = 0; g < 16; g += 4) dft4<INV>(x + g);
}
// inputs t>=8 are zero (only x[0..7] read)
template<bool INV>
__device__ __forceinline__ void dft16_h8(cpx* x){
    #pragma unroll
    for (int j2 = 0; j2 < 4; ++j2){
        cpx y[4];
        y[0] = x[j2]; y[1] = x[j2+4];
        dft4_h2<INV>(y);
        if (j2){
            #pragma unroll
            for (int r = 1; r < 4; ++r) y[r] = twmul<INV>(y[r], 32*j2*r);
        }
        x[j2] = y[0]; x[j2+4] = y[1]; x[j2+8] = y[2]; x[j2+12] = y[3];
    }
    #pragma unroll
    for (int g = 0; g < 16; g += 4) dft4<INV>(x + g);
}
// only bins k<8 produced (valid registers prm(k) for k<8)
template<bool INV>
__device__ __forceinline__ void dft16_lo8(cpx* x){
    #pragma unroll
    for (int j2 = 0; j2 < 4; ++j2){
        cpx y[4] = {x[j2], x[j2+4], x[j2+8], x[j2+12]};
        dft4<INV>(y);
        if (j2){
            #pragma unroll
            for (int r = 1; r < 4; ++r) y[r] = twmul<INV>(y[r], 32*j2*r);
        }
        x[j2] = y[0]; x[j2+4] = y[1]; x[j2+8] = y[2]; x[j2+12] = y[3];
    }
    #pragma unroll
    for (int g = 0; g < 16; g += 4) dft4_lo2<INV>(x + g);
}

// ---------------- radix-8 butterflies (cpx, for the z kernels) ----------------
template<bool INV>
__device__ __forceinline__ void dft8(cpx* x){
    const float s = 0.70710678118654752440f;
    cpx e0 = x[0] + x[4], e2 = x[0] - x[4];
    cpx e1 = x[2] + x[6], e3 = x[2] - x[6];
    cpx E0 = e0 + e1, E2 = e0 - e1;
    cpx j3 = INV ? cmpi(e3) : cmji(e3);
    cpx E1 = e2 + j3, E3 = e2 - j3;
    cpx o0 = x[1] + x[5], o2 = x[1] - x[5];
    cpx o1 = x[3] + x[7], o3 = x[3] - x[7];
    cpx O0 = o0 + o1, O2 = o0 - o1;
    cpx k3 = INV ? cmpi(o3) : cmji(o3);
    cpx O1 = o2 + k3, O3 = o2 - k3;
    cpx W1, W2, W3;
    if (!INV){
        W1 = s*(O1 + cmji(O1));
        W2 = cmji(O2);
        W3 = s*(cmji(O3) - O3);
    } else {
        W1 = s*(O1 + cmpi(O1));
        W2 = cmpi(O2);
        W3 = s*(cmpi(O3) - O3);
    }
    x[0] = E0 + O0; x[4] = E0 - O0;
    x[1] = E1 + W1; x[5] = E1 - W1;
    x[2] = E2 + W2; x[6] = E2 - W2;
    x[3] = E3 + W3; x[7] = E3 - W3;
}
template<bool INV>
__device__ __forceinline__ void dft8_h4(cpx* x){
    const float s = 0.70710678118654752440f;
    cpx a0 = x[0], a1 = x[1], a2 = x[2], a3 = x[3];
    cpx E0 = a0 + a2, E2 = a0 - a2;
    cpx j3 = INV ? cmpi(a2) : cmji(a2);
    cpx E1 = a0 + j3, E3 = a0 - j3;
    cpx O0 = a1 + a3, O2 = a1 - a3;
    cpx k3 = INV ? cmpi(a3) : cmji(a3);
    cpx O1 = a1 + k3, O3 = a1 - k3;
    cpx W1, W2, W3;
    if (!INV){
        W1 = s*(O1 + cmji(O1));
        W2 = cmji(O2);
        W3 = s*(cmji(O3) - O3);
    } else {
        W1 = s*(O1 + cmpi(O1));
        W2 = cmpi(O2);
        W3 = s*(cmpi(O3) - O3);
    }
    x[0] = E0 + O0; x[4] = E0 - O0;
    x[1] = E1 + W1; x[5] = E1 - W1;
    x[2] = E2 + W2; x[6] = E2 - W2;
    x[3] = E3 + W3; x[7] = E3 - W3;
}
template<bool INV>
__device__ __forceinline__ void dft8_lo4(cpx* x){
    const float s = 0.70710678118654752440f;
    cpx e0 = x[0] + x[4], e2 = x[0] - x[4];
    cpx e1 = x[2] + x[6], e3 = x[2] - x[6];
    cpx E0 = e0 + e1, E2 = e0 - e1;
    cpx j3 = INV ? cmpi(e3) : cmji(e3);
    cpx E1 = e2 + j3, E3 = e2 - j3;
    cpx o0 = x[1] + x[5], o2 = x[1] - x[5];
    cpx o1 = x[3] + x[7], o3 = x[3] - x[7];
    cpx O0 = o0 + o1, O2 = o0 - o1;
    cpx k3 = INV ? cmpi(o3) : cmji(o3);
    cpx O1 = o2 + k3, O3 = o2 - k3;
    cpx W1, W2, W3;
    if (!INV){
        W1 = s*(O1 + cmji(O1));
        W2 = cmji(O2);
        W3 = s*(cmji(O3) - O3);
    } else {
        W1 = s*(O1 + cmpi(O1));
        W2 = cmpi(O2);
        W3 = s*(cmpi(O3) - O3);
    }
    x[0] = E0 + O0;
    x[1] = E1 + W1;
    x[2] = E2 + W2;
    x[3] = E3 + W3;
}

// ---------------- 256-pt radix-4 FFT stages 1..3 on a contiguous LDS line ----------------
template<bool INV, bool CROP>
__device__ __forceinline__ void fft256_r4_tail(cpx* sl, int b){
    cpx x[4];
    {   // stage 1: stride 16, tw W_512^{8*j*r}
        int j = b & 15, g = (b >> 4) << 6;
        #pragma unroll
        for (int t = 0; t < 4; ++t) x[t] = sl[g + j + (t << 4)];
        dft4<INV>(x);
        #pragma unroll
        for (int r = 1; r < 4; ++r) x[r] = twmul<INV>(x[r], 8*j*r);
        #pragma unroll
        for (int r = 0; r < 4; ++r) sl[g + j + (r << 4)] = x[r];
    }
    __syncthreads();
    {   // stage 2: stride 4, tw W_512^{32*j*r}
        int j = b & 3, g = (b >> 2) << 4;
        #pragma unroll
        for (int t = 0; t < 4; ++t) x[t] = sl[g + j + (t << 2)];
        dft4<INV>(x);
        #pragma unroll
        for (int r = 1; r < 4; ++r) x[r] = twmul<INV>(x[r], 32*j*r);
        #pragma unroll
        for (int r = 0; r < 4; ++r) sl[g + j + (r << 2)] = x[r];
    }
    __syncthreads();
    {   // stage 3: stride 1, no twiddle
        int g = b << 2;
        #pragma unroll
        for (int t = 0; t < 4; ++t) x[t] = sl[g + t];
        if (CROP){
            dft4_lo2<INV>(x);
            sl[g] = x[0]; sl[g + 1] = x[1];
        } else {
            dft4<INV>(x);
            #pragma unroll
            for (int r = 0; r < 4; ++r) sl[g + r] = x[r];
        }
    }
    __syncthreads();
}

// ---------------- forward x-FFT fused with fill; store x-fftshifted AND x-half-blurred ----------------
__global__ __launch_bounds__(256) void k_fft_x_fill(const float* __restrict__ feat, cpx* __restrict__ V){
    __shared__ cpx s[4*256];                     // 8 KiB
    int tid = threadIdx.x;
    int line0 = blockIdx.x << 2;                 // line = z*128 + y, z<256, y<128
    int l = tid >> 6, b = tid & 63;
    int line = line0 + l;
    cpx* sl = s + l*256;
    {   // stage 0 from global: inputs positions b, b+64 (support x<128)
        int z = line >> 7;
        float g = (float)z*(1.0f/255.0f);
        const float* fl = feat + ((size_t)line << 7);
        float a  = fl[b]*g*g;       a  = a  > 0.0f ? sqrtf(a)  : 0.0f;
        float bb = fl[b + 64]*g*g;  bb = bb > 0.0f ? sqrtf(bb) : 0.0f;
        cpx x[4];
        x[0] = (cpx){a, 0.0f};
        x[1] = (cpx){bb, 0.0f};
        dft4_h2<false>(x);
        #pragma unroll
        for (int r = 1; r < 4; ++r) x[r] = twmul<false>(x[r], 2*b*r);
        #pragma unroll
        for (int r = 0; r < 4; ++r) sl[b + (r << 6)] = x[r];
    }
    __syncthreads();
    fft256_r4_tail<false, false>(sl, b);
    // blurred shifted store: F_s[e] sits at LDS pos rev4_8(e)^2 (rev4_8(128)=2)
    for (int i = tid; i < 4*128; i += 256){
        int ll = i >> 7, f4 = i & 127;
        int lin = line0 + ll;
        int base = ((lin >> 7) << 16) + ((lin & 127) << 8);
        const cpx* sll = s + ll*256;
        int e0 = 2*f4;
        cpx Fm = e0 ? sll[rev4_8(e0 - 1) ^ 2] : (cpx){0.0f, 0.0f};
        cpx F0 = sll[rev4_8(e0) ^ 2];
        cpx F1 = sll[rev4_8(e0 + 1) ^ 2];
        cpx o0 = 0.5f*(Fm + F0);
        cpx o1 = 0.5f*(F0 + F1);
        float4 o = make_float4(o0.x, o0.y, o1.x, o1.y);
        ((float4*)(V + base))[f4] = o;
    }
}

// ---------------- final inverse x-FFT fused with |.|^2, crop x<128; 4 lines/block ----------------
__global__ __launch_bounds__(256) void k_fft_x_inv_mag(const cpx* __restrict__ W,
                                                       float* __restrict__ out){
    __shared__ cpx s[4*256];                     // 8 KiB
    int tid = threadIdx.x;
    int line0 = blockIdx.x << 2;
    int l = tid >> 6, b = tid & 63;
    int line = line0 + l;
    int base = ((line >> 7) << 16) + ((line & 127) << 8);
    cpx* sl = s + l*256;
    {   // stage 0 from global: rows b+64t
        cpx x[4];
        #pragma unroll
        for (int t = 0; t < 4; ++t) x[t] = W[base + b + (t << 6)];
        dft4<true>(x);
        #pragma unroll
        for (int r = 1; r < 4; ++r) x[r] = twmul<true>(x[r], 2*b*r);
        #pragma unroll
        for (int r = 0; r < 4; ++r) sl[b + (r << 6)] = x[r];
    }
    __syncthreads();
    fft256_r4_tail<true, true>(sl, b);
    {
        int z = line >> 7, y = line & 127;
        cpx v0 = sl[rev4_8(2*b)];
        cpx v1 = sl[rev4_8(2*b + 1)];
        const float SC2 = (1.0f/33554432.0f)*(1.0f/33554432.0f);   // (1/(512*256*256))^2
        float2 o = make_float2((v0.x*v0.x + v0.y*v0.y)*SC2,
                               (v1.x*v1.x + v1.y*v1.y)*SC2);
        ((float2*)(out + (((size_t)(z*128 + y)) << 7)))[b] = o;
    }
}

// ---------------- FFT along y: RADIX-16, 2 stages, 256 threads, tile 16 x, fixed z ----------------
// c = tid&15 (column), j = tid>>4 (butterfly/group index in [0,16)).
// Stage 0: rows j+16t from global -> dft16 (h8 fwd) -> outer tw W_512^{2jr} -> LDS row j+16r.
// Stage 1: thread-owned rows 16j..16j+15 (no cross-thread hazard), in-place dft16.
// Forward: stage-1 leaves bin prm(u)*16+j at row 16j+u; blurred epilogue maps
// row_of_bin(K) = ((K&15)<<4) | prm(K>>4). Inverse: dft16_lo8 + direct global store.
#define YROW 18   // LDS row stride in cpx (144 B: even -> cpx2-aligned)
template<bool INV, bool HALF_IN, bool HALF_OUT>
__global__ __launch_bounds__(256, 4) void k_fft_y(cpx* __restrict__ V){
    __shared__ cpx s[256*YROW];                 // 36 KiB
    int tid = threadIdx.x;
    int z  = blockIdx.x >> 4;
    int x0 = (blockIdx.x & 15) << 4;
    int base = (z << 16) + x0;
    int c = tid & 15, j = tid >> 4;
    cpx x[16];
    {   // stage 0
        if (HALF_IN){
            #pragma unroll
            for (int t = 0; t < 8; ++t) x[t] = V[base + ((j + (t << 4)) << 8) + c];
            dft16_h8<INV>(x);
        } else {
            #pragma unroll
            for (int t = 0; t < 16; ++t) x[t] = V[base + ((j + (t << 4)) << 8) + c];
            dft16<INV>(x);
        }
        #pragma unroll
        for (int r = 1; r < 16; ++r) x[prm(r)] = twmul<INV>(x[prm(r)], 2*j*r);
        #pragma unroll
        for (int r = 0; r < 16; ++r) s[(j + (r << 4))*YROW + c] = x[prm(r)];
    }
    __syncthreads();
    int g = j << 4;
    if (HALF_OUT){
        // stage 1 + crop: bins K = 16*sb + j, sb<8; direct store (no LDS write)
        #pragma unroll
        for (int t = 0; t < 16; ++t) x[t] = s[(g + t)*YROW + c];
        dft16_lo8<INV>(x);
        #pragma unroll
        for (int sb = 0; sb < 8; ++sb)
            V[base + (((sb << 4) | j) << 8) + c] = x[prm(sb)];
        return;
    }
    {   // stage 1 full, in-place on own rows
        #pragma unroll
        for (int t = 0; t < 16; ++t) x[t] = s[(g + t)*YROW + c];
        dft16<INV>(x);
        #pragma unroll
        for (int u = 0; u < 16; ++u) s[(g + u)*YROW + c] = x[u];   // row g+u holds bin prm(u)*16+j
    }
    __syncthreads();
    // blurred shifted store: pos e = 0.5*(F_s[e-1] + F_s[e]); F_s[q] = bin(q^128)
    for (int i = tid; i < 256*8; i += 256){
        int f4c = i & 7, e = i >> 3;
        int k0 = e ^ 128;
        int r0 = ((k0 & 15) << 4) | prm(k0 >> 4);
        cpx2 S0 = ((const cpx2*)(s + r0*YROW))[f4c];
        cpx2 S1 = (cpx2){0.0f, 0.0f, 0.0f, 0.0f};
        if (e){
            int k1 = (e - 1) ^ 128;
            int r1 = ((k1 & 15) << 4) | prm(k1 >> 4);
            S1 = ((const cpx2*)(s + r1*YROW))[f4c];
        }
        cpx2 o = 0.5f*(S0 + S1);
        ((cpx2*)(V + base + (e << 8)))[f4c] = o;
    }
}

// ---------------- FUSED z-stage: fwd z-FFT (partner source column) + Stolt gather +
// inverse z-FFT, one 64 KiB buffer, 6 barriers. Reads planes 0..255 only; writes dest
// to planes 256..511 (disjoint -> race-free across blocks). ----------------
__global__ __launch_bounds__(1024, 8) void k_fftz_fused(cpx* __restrict__ V){
    __shared__ cpx s[512*16];                   // 64 KiB
    int tid = threadIdx.x;
    int yD  = blockIdx.x >> 4;
    int x0D = (blockIdx.x & 15) << 4;
    int baseD = (yD << 8) + x0D;
    int yS  = (yD + 128) & 255;
    int x0S = (x0D + 128) & 255;                // 16-aligned; x0S+c stays in tile
    int baseS = (yS << 8) + x0S;
    int c = tid & 15, idx = tid >> 4;
    cpx x[8];
    int j = idx;
    {   // fwd stage 0: source planes j+64t (t<4 nonzero) straight from global
        #pragma unroll
        for (int t = 0; t < 4; ++t)
            x[t] = V[baseS + (((size_t)(j + (t << 6))) << 16) + c];
        dft8_h4<false>(x);
        #pragma unroll
        for (int r = 1; r < 8; ++r) x[r] = twmul<false>(x[r], j*r);
        #pragma unroll
        for (int r = 0; r < 8; ++r) s[(j + (r << 6))*16 + c] = x[r];
    }
    __syncthreads();
    {   // fwd stage 1
        int jj = idx & 7, g = (idx >> 3) << 6;
        #pragma unroll
        for (int t = 0; t < 8; ++t) x[t] = s[(g + jj + (t << 3))*16 + c];
        dft8<false>(x);
        #pragma unroll
        for (int r = 1; r < 8; ++r) x[r] = twmul<false>(x[r], 8*jj*r);
        #pragma unroll
        for (int r = 0; r < 8; ++r) s[(g + jj + (r << 3))*16 + c] = x[r];
    }
    __syncthreads();
    {   // fwd stage 2 lo4: write bins 0..255 at NATURAL rows e = rev8(position)
        int g = idx << 3;
        #pragma unroll
        for (int t = 0; t < 8; ++t) x[t] = s[(g + t)*16 + c];
        dft8_lo4<false>(x);
        #pragma unroll
        for (int r = 0; r < 4; ++r){
            int e = (r << 6) | ((idx & 7) << 3) | (idx >> 3);   // rev8_9(g+r), < 256
            s[e*16 + c] = x[r];
        }
    }
    __syncthreads();
    // Stolt gather (dest coords = source position) -> inverse stage-0 registers
    {
        int xs = x0S + c;
        float gx = (float)(xs - 128)*(1.0f/128.0f);
        float gy = (float)(yS - 128)*(1.0f/128.0f);
        float rxy = 0.1024f*(gx*gx + gy*gy);
        #pragma unroll
        for (int t = 0; t < 4; ++t){
            int zd = j + (t << 6);
            cpx r = (cpx){0.0f, 0.0f};
            if (zd){
                float gz = (float)zd*(1.0f/256.0f);
                float gzn = sqrtf(rxy + gz*gz);
                float iz = ((gzn + 1.0f)*512.0f - 1.0f)*0.5f;
                float fiz = floorf(iz);
                int iz0 = (int)fiz;              // in [256, ~536)
                float fz = iz - fiz;
                float sc = gz/(gzn + 1e-8f);
                int b0 = (iz0 < 511 ? iz0 : 511) - 256;
                int b1 = ((iz0 + 1) < 511 ? (iz0 + 1) : 511) - 256;
                float w0 = (iz0     <= 511) ? (1.0f - fz)*sc : 0.0f;
                float w1 = (iz0 + 1 <= 511) ? fz*sc : 0.0f;
                cpx a = s[(b0 << 4) + c];        // natural-row fwd bins
                cpx b = s[(b1 << 4) + c];
                r = a*w0 + b*w1;
            }
            x[t] = r;
        }
        dft8_h4<true>(x);
        #pragma unroll
        for (int r = 1; r < 8; ++r) x[r] = twmul<true>(x[r], j*r);
    }
    __syncthreads();                             // all gather reads done before overwrite
    {
        #pragma unroll
        for (int r = 0; r < 8; ++r) s[(j + (r << 6))*16 + c] = x[r];
    }
    __syncthreads();
    {   // inv stage 1
        int jj = idx & 7, g = (idx >> 3) << 6;
        #pragma unroll
        for (int t = 0; t < 8; ++t) x[t] = s[(g + jj + (t << 3))*16 + c];
        dft8<true>(x);
        #pragma unroll
        for (int r = 1; r < 8; ++r) x[r] = twmul<true>(x[r], 8*jj*r);
        #pragma unroll
        for (int r = 0; r < 8; ++r) s[(g + jj + (r << 3))*16 + c] = x[r];
    }
    __syncthreads();
    {   // inv stage 2 lo4 + DIRECT store of z<256 to dest planes 256..511
        int g = idx << 3;
        #pragma unroll
        for (int t = 0; t < 8; ++t) x[t] = s[(g + t)*16 + c];
        dft8_lo4<true>(x);
        #pragma unroll
        for (int r = 0; r < 4; ++r){
            int e = (r << 6) | ((idx & 7) << 3) | (idx >> 3);   // rev8_9(g+r), < 256
            V[baseD + (((size_t)(e + 256)) << 16) + c] = x[r];
        }
    }
}

extern "C" void kernel_launch(void* const* d_in, const int* in_sizes, int n_in,
                              void* d_out, int out_size, void* d_ws, size_t ws_size,
                              hipStream_t stream){
    const float* feat = (const float*)d_in[0];   // [1,1,256,128,128] f32; tbes=0, tens=256
    float* out = (float*)d_out;                  // [1,1,256,128,128] f32

    const size_t WS_NEED = (size_t)512*256*256*8;   // 268,435,456 B exactly
    if (ws_size < WS_NEED){
        hipMemsetAsync(d_out, 0, (size_t)out_size*sizeof(float), stream);
        return;
    }
    cpx* V  = (cpx*)d_ws;
    cpx* Vu = V + (size_t)256*65536;             // planes 256..511 (post-z result)

    k_tw<<<1, 512, 0, stream>>>();
    // forward x (+fill,+x-blur) and y (+y-blur), stored fftshifted, planes 0..255
    k_fft_x_fill<<<8192, 256, 0, stream>>>(feat, V);                // 4 lines/block
    k_fft_y<false, true, false><<<4096, 256, 0, stream>>>(V);       // z<256; y<128 in, blurred y out
    // fused z-stage: fwd FFT of partner column + gather + inv FFT -> planes 256..511
    k_fftz_fused<<<4096, 1024, 0, stream>>>(V);
    // inverse y + inverse x (+|.|^2) on planes 256..511 via offset base pointer
    k_fft_y<true, false, true><<<4096, 256, 0, stream>>>(Vu);       // full y in, y<128 out (direct store)
    k_fft_x_inv_mag<<<8192, 256, 0, stream>>>(Vu, out);             // 4 lines/block, |.|^2, x<128
}